// Round 1
// baseline (1959.824 us; speedup 1.0000x reference)
//
#include <hip/hip_runtime.h>
#include <cstdint>
#include <cstddef>

#define BB 8
#define NN 16384
#define SS 512
#define KK 32

__device__ __forceinline__ float fm(float a, float b){ return __fmul_rn(a,b); }
__device__ __forceinline__ float fa(float a, float b){ return __fadd_rn(a,b); }
__device__ __forceinline__ float fsb(float a, float b){ return __fsub_rn(a,b); }

// ---------------- per-point squared norm (numpy order: (x^2+y^2)+z^2) ----------------
__global__ void sqnorm_kernel(const float* __restrict__ xyz, float* __restrict__ sqn){
  int gid = blockIdx.x*blockDim.x + threadIdx.x; // B*N
  int b = gid >> 14; int n = gid & (NN-1);
  const float* xb = xyz + (size_t)b*3*NN;
  float x = xb[n], y = xb[NN+n], z = xb[2*NN+n];
  sqn[gid] = fa(fa(fm(x,x),fm(y,y)),fm(z,z));
}

// ---------------- farthest point sampling: 1 block per batch ----------------
__global__ __launch_bounds__(512) void fps_kernel(const float* __restrict__ xyz,
                                                  float* __restrict__ nxyz,   // ws (B,S,3)
                                                  float* __restrict__ out)    // d_out (B,3,S)
{
  int b = blockIdx.x;
  int t = threadIdx.x;
  const float* xb = xyz + (size_t)b*3*NN;
  float px[32], py[32], pz[32], dist[32];
#pragma unroll
  for (int k=0;k<32;k++){
    int n = k*512 + t;
    px[k]=xb[n]; py[k]=xb[NN+n]; pz[k]=xb[2*NN+n];
    dist[k]=1e10f;
  }
  __shared__ float swv[8];
  __shared__ int swi[8];
  __shared__ int scur;
  int cur = 0;
  for (int step=0; step<SS; ++step){
    float cx = xb[cur], cy = xb[NN+cur], cz = xb[2*NN+cur];
    if (t==0){
      float* nx = nxyz + ((size_t)b*SS + step)*3;
      nx[0]=cx; nx[1]=cy; nx[2]=cz;
      float* ox = out + (size_t)b*3*SS;
      ox[step]=cx; ox[SS+step]=cy; ox[2*SS+step]=cz;
    }
    float bv = -1.0f; int bi = 0;
#pragma unroll
    for (int k=0;k<32;k++){
      float dx=fsb(px[k],cx), dy=fsb(py[k],cy), dz=fsb(pz[k],cz);
      float d = fa(fa(fm(dx,dx),fm(dy,dy)),fm(dz,dz));
      float dk = fminf(dist[k], d);
      dist[k]=dk;
      // strict > keeps earliest k => smallest index for this thread (idx grows with k)
      if (dk > bv){ bv=dk; bi=k*512+t; }
    }
    // wave(64) argmax reduce, first-index tie-break
#pragma unroll
    for (int off=32; off>=1; off>>=1){
      float ov = __shfl_down(bv, off);
      int   oi = __shfl_down(bi, off);
      if (ov > bv || (ov == bv && oi < bi)){ bv=ov; bi=oi; }
    }
    int wid = t >> 6;
    if ((t & 63)==0){ swv[wid]=bv; swi[wid]=bi; }
    __syncthreads();
    if (t==0){
      float v=swv[0]; int i=swi[0];
#pragma unroll
      for (int w=1;w<8;w++){
        if (swv[w] > v || (swv[w]==v && swi[w]<i)){ v=swv[w]; i=swi[w]; }
      }
      scur=i;
    }
    __syncthreads();
    cur = scur;
  }
}

// ---------------- ball query: 1 wave per centroid, early exit at 32 hits ----------------
__global__ void ballq_kernel(const float* __restrict__ xyz,
                             const float* __restrict__ sqn,
                             const float* __restrict__ nxyz,
                             int* __restrict__ gidx)
{
  int wv = (blockIdx.x * (blockDim.x>>6)) + (threadIdx.x>>6); // B*S waves
  int lane = threadIdx.x & 63;
  int b = wv >> 9; int s = wv & (SS-1);
  const float* nx3 = nxyz + ((size_t)b*SS + s)*3;
  float nx=nx3[0], ny=nx3[1], nz=nx3[2];
  float cn = fa(fa(fm(nx,nx),fm(ny,ny)),fm(nz,nz));
  const float* xb = xyz + (size_t)b*3*NN;
  const float* sb = sqn + (size_t)b*NN;
  const float R2 = (float)(0.2*0.2);   // f64 product rounded once to f32
  int* g = gidx + ((size_t)b*SS + s)*KK;
  int cnt = 0; int first_idx = 0;
  for (int base=0; base<NN; base+=64){
    int n = base + lane;
    float x=xb[n], y=xb[NN+n], z=xb[2*NN+n];
    float dot = fa(fa(fm(nx,x),fm(ny,y)),fm(nz,z));
    float sqd = fsb(fa(cn, sb[n]), fm(2.0f, dot));
    bool inb = !(sqd > R2);
    unsigned long long m = __ballot(inb);
    if (m){
      if (cnt==0) first_idx = base + __builtin_ctzll(m);
      int pre = __popcll(m & ((1ull<<lane)-1ull));
      int slot = cnt + pre;
      if (inb && slot < KK) g[slot] = n;
      cnt += __popcll(m);
      if (cnt >= KK) break;
    }
  }
  if (cnt < KK && lane >= cnt && lane < KK) g[lane] = first_idx;
}

// ---------------- layer 0: gather + concat + conv(6->64) ----------------
__global__ __launch_bounds__(256) void mlp0_kernel(const float* __restrict__ xyz,
                            const float* __restrict__ pts,
                            const float* __restrict__ nxyz,
                            const int* __restrict__ gidx,
                            const float* __restrict__ w,    // (64,6)
                            const float* __restrict__ bias,
                            float* __restrict__ y0)         // (B,64,K,S)
{
  int gid = blockIdx.x*blockDim.x + threadIdx.x;  // B*K*S
  int b = gid / (KK*SS);
  int r = gid % (KK*SS);
  int k = r / SS; int s = r % SS;
  int idx = gidx[((size_t)b*SS + s)*KK + k];
  const float* pb = pts + (size_t)b*3*NN;
  const float* xb = xyz + (size_t)b*3*NN;
  const float* nx3 = nxyz + ((size_t)b*SS + s)*3;
  float in[6];
  in[0]=pb[idx]; in[1]=pb[NN+idx]; in[2]=pb[2*NN+idx];
  in[3]=xb[idx]-nx3[0]; in[4]=xb[NN+idx]-nx3[1]; in[5]=xb[2*NN+idx]-nx3[2];
  float* po = y0 + (size_t)b*64*KK*SS + r;
  for (int o=0;o<64;o++){
    float acc = bias[o];
#pragma unroll
    for (int c=0;c<6;c++) acc += in[c]*w[o*6+c];
    po[(size_t)o*KK*SS] = acc;
  }
}

// ---------------- BN stats: one block per channel ----------------
__global__ __launch_bounds__(256) void stats_kernel(const float* __restrict__ y, int C,
                             const float* __restrict__ gamma,
                             const float* __restrict__ beta,
                             float* __restrict__ a, float* __restrict__ c)
{
  int o = blockIdx.x; int t = threadIdx.x;
  double s1=0.0, s2=0.0;
  for (int b=0;b<BB;b++){
    const float* p = y + ((size_t)b*C + o)*KK*SS;
    for (int j=t; j<KK*SS; j+=256){ float v=p[j]; s1 += (double)v; s2 += (double)v*(double)v; }
  }
#pragma unroll
  for (int off=32; off>=1; off>>=1){
    s1 += __shfl_down(s1, off);
    s2 += __shfl_down(s2, off);
  }
  __shared__ double l1[4], l2[4];
  int wid = t>>6;
  if ((t&63)==0){ l1[wid]=s1; l2[wid]=s2; }
  __syncthreads();
  if (t==0){
    double t1=0,t2=0;
    for (int w=0;w<4;w++){ t1+=l1[w]; t2+=l2[w]; }
    double n = (double)BB*KK*SS;
    double m = t1/n;
    double var = t2/n - m*m;
    double inv = 1.0/sqrt(var + 1e-5);
    float sc = (float)((double)gamma[o]*inv);
    a[o]=sc; c[o]=(float)((double)beta[o] - m*(double)sc);
  }
}

// ---------------- conv layer: BN+ReLU applied to input on the fly ----------------
template<int CIN, int COUT>
__global__ __launch_bounds__(256) void mlp_kernel(const float* __restrict__ yin,
                            const float* __restrict__ w,
                            const float* __restrict__ bias,
                            const float* __restrict__ a,
                            const float* __restrict__ cc,
                            float* __restrict__ yout)
{
  int gid = blockIdx.x*blockDim.x + threadIdx.x; // B*K*S
  int b = gid / (KK*SS);
  int r = gid % (KK*SS);
  const float* pin = yin + (size_t)b*CIN*KK*SS + r;
  float x[CIN];
#pragma unroll
  for (int ci=0;ci<CIN;ci++) x[ci] = fmaxf(fmaf(pin[(size_t)ci*KK*SS], a[ci], cc[ci]), 0.0f);
  float* po = yout + (size_t)b*COUT*KK*SS + r;
  for (int o=0;o<COUT;o++){
    float acc = bias[o];
#pragma unroll
    for (int ci=0;ci<CIN;ci++) acc += x[ci]*w[o*CIN+ci];
    po[(size_t)o*KK*SS] = acc;
  }
}

// ---------------- final: BN+ReLU+max over K ----------------
__global__ __launch_bounds__(256) void final_kernel(const float* __restrict__ y2,
                             const float* __restrict__ a,
                             const float* __restrict__ cc,
                             float* __restrict__ out)  // (B,128,S)
{
  int gid = blockIdx.x*blockDim.x + threadIdx.x; // B*128*S
  int b = gid / (128*SS);
  int r = gid % (128*SS);
  int o = r / SS; int s = r % SS;
  const float* p = y2 + ((size_t)b*128 + o)*KK*SS + s;
  float sc=a[o], sh=cc[o];
  float m = 0.0f;  // relu outputs are >= 0, 32 values exist
#pragma unroll
  for (int k=0;k<KK;k++){
    float v = fmaf(p[(size_t)k*SS], sc, sh);
    v = fmaxf(v, 0.0f);
    m = fmaxf(m, v);
  }
  out[gid] = m;
}

extern "C" void kernel_launch(void* const* d_in, const int* in_sizes, int n_in,
                              void* d_out, int out_size, void* d_ws, size_t ws_size,
                              hipStream_t stream)
{
  const float* xyz = (const float*)d_in[0];
  const float* pts = (const float*)d_in[1];
  const float* w0  = (const float*)d_in[2];
  const float* b0  = (const float*)d_in[3];
  const float* g0  = (const float*)d_in[4];
  const float* be0 = (const float*)d_in[5];
  const float* w1  = (const float*)d_in[6];
  const float* b1  = (const float*)d_in[7];
  const float* g1  = (const float*)d_in[8];
  const float* be1 = (const float*)d_in[9];
  const float* w2  = (const float*)d_in[10];
  const float* b2  = (const float*)d_in[11];
  const float* g2  = (const float*)d_in[12];
  const float* be2 = (const float*)d_in[13];
  float* out = (float*)d_out;

  char* ws = (char*)d_ws;
  float* sqn  = (float*)(ws + 0);          // B*N f32          = 524288 B
  float* nxyz = (float*)(ws + 524288);     // B*S*3 f32        = 49152 B
  int*   gidx = (int*)  (ws + 573440);     // B*S*K i32        = 524288 B
  float* st   = (float*)(ws + 1097728);    // 512 f32
  float* a0=st,     *c0=st+64;
  float* a1=st+128, *c1=st+192;
  float* a2=st+256, *c2=st+384;
  // y1 at 4MiB (33.5MB), y2 at 40MiB (67MB), y0 at 76MiB (33.5MB; dead before y2 written)
  float* y1 = (float*)(ws + 4194304);
  float* y2 = (float*)(ws + 41943040);
  float* y0 = (float*)(ws + 79691776);
  (void)ws_size; (void)in_sizes; (void)n_in; (void)out_size;

  sqnorm_kernel<<<dim3(512), dim3(256), 0, stream>>>(xyz, sqn);
  fps_kernel<<<dim3(BB), dim3(512), 0, stream>>>(xyz, nxyz, out);
  ballq_kernel<<<dim3(1024), dim3(256), 0, stream>>>(xyz, sqn, nxyz, gidx);
  mlp0_kernel<<<dim3(512), dim3(256), 0, stream>>>(xyz, pts, nxyz, gidx, w0, b0, y0);
  stats_kernel<<<dim3(64), dim3(256), 0, stream>>>(y0, 64, g0, be0, a0, c0);
  mlp_kernel<64,64><<<dim3(512), dim3(256), 0, stream>>>(y0, w1, b1, a0, c0, y1);
  stats_kernel<<<dim3(64), dim3(256), 0, stream>>>(y1, 64, g1, be1, a1, c1);
  mlp_kernel<64,128><<<dim3(512), dim3(256), 0, stream>>>(y1, w2, b2, a1, c1, y2);
  stats_kernel<<<dim3(128), dim3(256), 0, stream>>>(y2, 128, g2, be2, a2, c2);
  final_kernel<<<dim3(2048), dim3(256), 0, stream>>>(y2, a2, c2, out + BB*3*SS);
}